// Round 1
// baseline (132.890 us; speedup 1.0000x reference)
//
#include <hip/hip_runtime.h>
#include <hip/hip_bf16.h>

#define NN 4096
#define BM 128
#define BN 128
#define BK 32
#define LDST 40   // LDS row stride in bf16 elements (80 B: 16B-aligned, bank-friendly)
#define NB (NN / BM)

typedef __bf16 v8bf __attribute__((ext_vector_type(8)));
typedef __bf16 v4bf __attribute__((ext_vector_type(4)));
typedef float  v4f  __attribute__((ext_vector_type(4)));

__global__ __launch_bounds__(256)
void trimm_bf16_kernel(const float* __restrict__ A,
                       const float* __restrict__ B,
                       float* __restrict__ C) {
    const int bj = blockIdx.x;   // output col-tile
    const int bi = blockIdx.y;   // output row-tile
    const int t  = threadIdx.x;
    const long brow = (long)bi * BM;
    const long bcol = (long)bj * BN;

    if (bi > bj) {
        // Strictly-lower block of triu(): write exact zeros (d_out is poisoned).
        const float4 z = make_float4(0.f, 0.f, 0.f, 0.f);
        #pragma unroll
        for (int i = 0; i < 16; ++i) {
            int s  = i * 256 + t;          // 4096 float4 slots
            int r  = s >> 5;               // 32 float4 per row
            int c4 = (s & 31) << 2;
            *reinterpret_cast<float4*>(&C[(brow + r) * NN + bcol + c4]) = z;
        }
        return;
    }

    __shared__ __bf16 As[BM][LDST];   // As[m][k]
    __shared__ __bf16 Bs[BN][LDST];   // transposed: Bs[n][k]

    const int lane = t & 63;
    const int wave = t >> 6;
    const int wm = (wave >> 1) * 64;  // wave row offset in tile
    const int wn = (wave & 1) * 64;   // wave col offset in tile
    const int l15 = lane & 15;
    const int g   = lane >> 4;        // k-group 0..3

    // Staging maps
    const int arow = t >> 3;          // 0..31  (A row, +32*i)
    const int akc  = (t & 7) << 2;    // 0,4,...,28 (A k chunk)
    const int bn   = t & 31;          // B n base (+32*j)
    const int bkc  = (t >> 5) << 2;   // 0,4,...,28 (B k chunk)

    v4f acc[4][4];
    #pragma unroll
    for (int mf = 0; mf < 4; ++mf)
        #pragma unroll
        for (int nf = 0; nf < 4; ++nf)
            acc[mf][nf] = (v4f){0.f, 0.f, 0.f, 0.f};

    const long k0   = brow;                 // A[i][k]==0 for k<i
    const long kend = bcol + BN;            // B[k][j]==0 for k>j

    for (long kt = k0; kt < kend; kt += BK) {
        // ---- stage A: 128x32 fp32 -> bf16, 4 float4 loads/thread ----
        #pragma unroll
        for (int i = 0; i < 4; ++i) {
            int r = arow + 32 * i;
            float4 a4 = *reinterpret_cast<const float4*>(
                &A[(brow + r) * NN + kt + akc]);
            v4bf pk;
            pk[0] = (__bf16)a4.x; pk[1] = (__bf16)a4.y;
            pk[2] = (__bf16)a4.z; pk[3] = (__bf16)a4.w;
            *reinterpret_cast<v4bf*>(&As[r][akc]) = pk;
        }
        // ---- stage B transposed: 32x128 fp32 -> Bs[n][k] bf16 ----
        {
            float tmp[4][4];
            #pragma unroll
            for (int jj = 0; jj < 4; ++jj) {
                const float* Brow = B + (kt + bkc + jj) * NN + bcol + bn;
                #pragma unroll
                for (int j = 0; j < 4; ++j) tmp[j][jj] = Brow[32 * j];
            }
            #pragma unroll
            for (int j = 0; j < 4; ++j) {
                v4bf pk;
                pk[0] = (__bf16)tmp[j][0]; pk[1] = (__bf16)tmp[j][1];
                pk[2] = (__bf16)tmp[j][2]; pk[3] = (__bf16)tmp[j][3];
                *reinterpret_cast<v4bf*>(&Bs[bn + 32 * j][bkc]) = pk;
            }
        }
        __syncthreads();

        // ---- fragments + MFMA ----
        v8bf af[4], bfr[4];
        #pragma unroll
        for (int mf = 0; mf < 4; ++mf)
            af[mf] = *reinterpret_cast<const v8bf*>(&As[wm + mf * 16 + l15][g * 8]);
        #pragma unroll
        for (int nf = 0; nf < 4; ++nf)
            bfr[nf] = *reinterpret_cast<const v8bf*>(&Bs[wn + nf * 16 + l15][g * 8]);

        #pragma unroll
        for (int mf = 0; mf < 4; ++mf)
            #pragma unroll
            for (int nf = 0; nf < 4; ++nf)
                acc[mf][nf] = __builtin_amdgcn_mfma_f32_16x16x32_bf16(
                    af[mf], bfr[nf], acc[mf][nf], 0, 0, 0);
        __syncthreads();
    }

    // ---- epilogue: C/D layout col=lane&15, row=(lane>>4)*4+reg ----
    #pragma unroll
    for (int mf = 0; mf < 4; ++mf) {
        #pragma unroll
        for (int nf = 0; nf < 4; ++nf) {
            long row = brow + wm + mf * 16 + g * 4;
            long col = bcol + wn + nf * 16 + l15;
            #pragma unroll
            for (int r = 0; r < 4; ++r)
                C[(row + r) * NN + col] = acc[mf][nf][r];
        }
    }
}

extern "C" void kernel_launch(void* const* d_in, const int* in_sizes, int n_in,
                              void* d_out, int out_size, void* d_ws, size_t ws_size,
                              hipStream_t stream) {
    const float* A = (const float*)d_in[0];
    const float* B = (const float*)d_in[1];
    float* C = (float*)d_out;
    dim3 grid(NB, NB);
    trimm_bf16_kernel<<<grid, 256, 0, stream>>>(A, B, C);
}

// Round 2
// 116.162 us; speedup vs baseline: 1.1440x; 1.1440x over previous
//
#include <hip/hip_runtime.h>
#include <hip/hip_bf16.h>
#include <math.h>

#define NN 4096
#define BM 128
#define BN 128
#define BK 32
#define LDST 40   // LDS row stride in bf16 elements (80 B)
#define NB (NN / BM)          // 32
#define NUPPER ((NB*(NB+1))/2)   // 528
#define NLOWER ((NB*(NB-1))/2)   // 496

typedef __bf16 v8bf __attribute__((ext_vector_type(8)));
typedef __bf16 v4bf __attribute__((ext_vector_type(4)));
typedef float  v4f  __attribute__((ext_vector_type(4)));

__global__ __launch_bounds__(256)
void trimm_bf16_kernel(const float* __restrict__ A,
                       const float* __restrict__ B,
                       float* __restrict__ C) {
    const int id = blockIdx.x;
    const int t  = threadIdx.x;

    if (id >= NUPPER) {
        // -------- zero-fill a strictly-lower tile (bi > bj) --------
        int z = id - NUPPER;
        int bi = (int)((1.0 + sqrt(1.0 + 8.0 * (double)z)) * 0.5);
        while (bi * (bi - 1) / 2 > z) --bi;
        while ((bi + 1) * bi / 2 <= z) ++bi;
        int bj = z - bi * (bi - 1) / 2;
        const long brow = (long)bi * BM;
        const long bcol = (long)bj * BN;
        const float4 zv = make_float4(0.f, 0.f, 0.f, 0.f);
        #pragma unroll
        for (int i = 0; i < 16; ++i) {
            int s  = i * 256 + t;
            int r  = s >> 5;
            int c4 = (s & 31) << 2;
            *reinterpret_cast<float4*>(&C[(brow + r) * NN + bcol + c4]) = zv;
        }
        return;
    }

    // -------- map id -> (bi,bj), sorted by DESCENDING work (d = bj-bi) -----
    int q = (NUPPER - 1) - id;             // ascending-d rank from the end
    int d = (int)((65.0 - sqrt(4225.0 - 8.0 * (double)q)) * 0.5);
    if (d < 0) d = 0;
    if (d > NB - 1) d = NB - 1;
    while (d > 0 && 32 * d - d * (d - 1) / 2 > q) --d;
    while (d < NB - 1 && 32 * (d + 1) - (d + 1) * d / 2 <= q) ++d;
    const int bi = q - (32 * d - d * (d - 1) / 2);
    const int bj = bi + d;

    const long brow = (long)bi * BM;
    const long bcol = (long)bj * BN;

    __shared__ __bf16 As[2][BM][LDST];   // As[buf][m][k]
    __shared__ __bf16 Bs[2][BN][LDST];   // transposed: Bs[buf][n][k]

    const int lane = t & 63;
    const int wave = t >> 6;
    const int wm = (wave >> 1) * 64;
    const int wn = (wave & 1) * 64;
    const int l15 = lane & 15;
    const int g   = lane >> 4;

    const int arow = t >> 3;          // 0..31 (+32*i)
    const int akc  = (t & 7) << 2;
    const int bn   = t & 31;
    const int bkc  = (t >> 5) << 2;

    v4f acc[4][4];
    #pragma unroll
    for (int mf = 0; mf < 4; ++mf)
        #pragma unroll
        for (int nf = 0; nf < 4; ++nf)
            acc[mf][nf] = (v4f){0.f, 0.f, 0.f, 0.f};

    const long k0 = brow;             // A[i][k]==0 for k<i
    const int  nt = (d + 1) * (BM / BK);

    // staging registers
    float4 aR[4];
    float  bR[16];

    #define ISSUE_LOADS(KT)                                                   \
        {                                                                     \
            _Pragma("unroll")                                                 \
            for (int i = 0; i < 4; ++i)                                       \
                aR[i] = *reinterpret_cast<const float4*>(                     \
                    &A[(brow + arow + 32 * i) * NN + (KT) + akc]);            \
            _Pragma("unroll")                                                 \
            for (int jj = 0; jj < 4; ++jj) {                                  \
                const float* Brow = B + ((KT) + bkc + jj) * NN + bcol + bn;   \
                _Pragma("unroll")                                             \
                for (int j = 0; j < 4; ++j) bR[jj * 4 + j] = Brow[32 * j];    \
            }                                                                 \
        }

    #define WRITE_LDS(BUF)                                                    \
        {                                                                     \
            _Pragma("unroll")                                                 \
            for (int i = 0; i < 4; ++i) {                                     \
                v4bf pk;                                                      \
                pk[0] = (__bf16)aR[i].x; pk[1] = (__bf16)aR[i].y;             \
                pk[2] = (__bf16)aR[i].z; pk[3] = (__bf16)aR[i].w;             \
                *reinterpret_cast<v4bf*>(&As[BUF][arow + 32 * i][akc]) = pk;  \
            }                                                                 \
            _Pragma("unroll")                                                 \
            for (int j = 0; j < 4; ++j) {                                     \
                v4bf pk;                                                      \
                pk[0] = (__bf16)bR[0 * 4 + j]; pk[1] = (__bf16)bR[1 * 4 + j]; \
                pk[2] = (__bf16)bR[2 * 4 + j]; pk[3] = (__bf16)bR[3 * 4 + j]; \
                *reinterpret_cast<v4bf*>(&Bs[BUF][bn + 32 * j][bkc]) = pk;    \
            }                                                                 \
        }

    // prologue
    ISSUE_LOADS(k0);
    WRITE_LDS(0);
    __syncthreads();

    int cur = 0;
    for (int tk = 0; tk < nt; ++tk) {
        const bool more = (tk + 1 < nt);
        if (more) { ISSUE_LOADS(k0 + (long)(tk + 1) * BK); }

        v8bf af[4], bfr[4];
        #pragma unroll
        for (int mf = 0; mf < 4; ++mf)
            af[mf] = *reinterpret_cast<const v8bf*>(&As[cur][wm + mf * 16 + l15][g * 8]);
        #pragma unroll
        for (int nf = 0; nf < 4; ++nf)
            bfr[nf] = *reinterpret_cast<const v8bf*>(&Bs[cur][wn + nf * 16 + l15][g * 8]);

        #pragma unroll
        for (int mf = 0; mf < 4; ++mf)
            #pragma unroll
            for (int nf = 0; nf < 4; ++nf)
                acc[mf][nf] = __builtin_amdgcn_mfma_f32_16x16x32_bf16(
                    af[mf], bfr[nf], acc[mf][nf], 0, 0, 0);

        if (more) { WRITE_LDS(cur ^ 1); }
        __syncthreads();
        cur ^= 1;
    }

    // epilogue: C/D layout col=lane&15, row=(lane>>4)*4+reg
    #pragma unroll
    for (int mf = 0; mf < 4; ++mf) {
        #pragma unroll
        for (int nf = 0; nf < 4; ++nf) {
            long row = brow + wm + mf * 16 + g * 4;
            long col = bcol + wn + nf * 16 + l15;
            #pragma unroll
            for (int r = 0; r < 4; ++r)
                C[(row + r) * NN + col] = acc[mf][nf][r];
        }
    }
    #undef ISSUE_LOADS
    #undef WRITE_LDS
}

extern "C" void kernel_launch(void* const* d_in, const int* in_sizes, int n_in,
                              void* d_out, int out_size, void* d_ws, size_t ws_size,
                              hipStream_t stream) {
    const float* A = (const float*)d_in[0];
    const float* B = (const float*)d_in[1];
    float* C = (float*)d_out;
    trimm_bf16_kernel<<<dim3(NUPPER + NLOWER), 256, 0, stream>>>(A, B, C);
}